// Round 6
// baseline (48.605 us; speedup 1.0000x reference)
//
#include <hip/hip_runtime.h>
#include <math.h>

#define BATCH 32
#define CCH 3
#define HH 256
#define WW 256
#define HW (HH*WW)
#define NGN_IT 5
#define NM 45            // 21 (A sym 6x6) + 6 (q0) + 18 (R0 3x6)
#define TROWS 4          // tile rows per block
#define NTILE (HH/TROWS) // 64 tiles per batch
#define NTHR 256
#define NROWCP 38        // staged 1KB row-copies: 18 bf + 12 f_inp + 4 depth + 4 mask

__host__ __device__ constexpr int idxA(int i, int j) { return 6*i - i*(i+1)/2 + j; } // i<=j

typedef __attribute__((address_space(1))) const unsigned int gu32;
typedef __attribute__((address_space(3))) unsigned int lu32;

__device__ __forceinline__ void gload_lds16(const float* g, float* l) {
    // per-lane global src; wave-uniform LDS base; HW writes lane i -> l + i*16
    __builtin_amdgcn_global_load_lds((gu32*)g, (lu32*)l, 16, 0, 0);
}

// ---------------------------------------------------------------------------
// Stage 1: block = 4-row tile of one batch. ALL inputs staged to LDS via
// global_load_lds (zero VGPR landing cost): every wave issues ~10 row-copies
// back-to-back, ONE vmcnt drain at the barrier -> one latency exposure per
// block, overlapped across 4 resident blocks/CU. Compute phase is pure
// LDS-read + VALU with acc[45] in registers (~90 live, cap 128).
// ---------------------------------------------------------------------------
__global__ __launch_bounds__(NTHR, 4) void k_moments(
    const float* __restrict__ f_inp, const float* __restrict__ depth,
    const int* __restrict__ fidx, const float* __restrict__ Kmat,
    const float* __restrict__ bbox, const float* __restrict__ base_feat,
    float* __restrict__ partials)
{
    const int b   = blockIdx.y;
    const int h0  = blockIdx.x * TROWS;
    const int tid = threadIdx.x;

    __shared__ float bf_s [CCH][TROWS+2][WW];  // 18 KB (halo rows clamped)
    __shared__ float fin_s[CCH][TROWS][WW];    // 12 KB
    __shared__ float dpt_s[TROWS][WW];         //  4 KB
    __shared__ int   msk_s[TROWS][WW];         //  4 KB
    __shared__ float red[4*NM];                //  720 B   -> ~39.6 KB total

    const int wv = tid >> 6, ln = tid & 63;

    // --- stage all streams: wave-uniform row mapping, lane ln copies 16 B ---
    for (int o = wv; o < NROWCP; o += 4) {
        const float* src; float* dst;
        if (o < 18) {                       // base_feat rows h0-1 .. h0+4, clamped
            const int c = o / 6, k = o % 6;
            int srow = h0 - 1 + k;
            srow = srow < 0 ? 0 : (srow > HH-1 ? HH-1 : srow);
            src = base_feat + ((size_t)c*HH + srow)*WW;
            dst = &bf_s[c][k][0];
        } else if (o < 30) {                // f_inp rows h0 .. h0+3
            const int t = o - 18, c = t >> 2, r = t & 3;
            src = f_inp + (size_t)b*CCH*HW + ((size_t)c*HH + h0 + r)*WW;
            dst = &fin_s[c][r][0];
        } else if (o < 34) {                // depth
            const int r = o - 30;
            src = depth + (size_t)b*HW + (size_t)(h0 + r)*WW;
            dst = &dpt_s[r][0];
        } else {                            // mask (int, same 16B copies)
            const int r = o - 34;
            src = (const float*)(fidx + (size_t)b*HW + (size_t)(h0 + r)*WW);
            dst = (float*)&msk_s[r][0];
        }
        gload_lds16(src + ln*4, dst);
    }

    // scalar batch constants (SGPR-resident)
    const float fxv = Kmat[b*9+0], fyv = Kmat[b*9+4];
    const float cx  = Kmat[b*9+2], cy  = Kmat[b*9+5];
    const float bb0 = bbox[b*2+0], bb1 = bbox[b*2+1];
    const float ifx = __builtin_amdgcn_rcpf(fxv);
    const float ify = __builtin_amdgcn_rcpf(fyv);

    __syncthreads();   // single vmcnt(0) drain: everything in LDS

    const int lp = tid * 4;          // local pixel 0..1023
    const int lr = lp >> 8;          // local row 0..3
    const int w0 = lp & (WW-1);      // col, multiple of 4
    const int h  = h0 + lr;

    // per-thread geometry from LDS
    const float4 zv = *(const float4*)&dpt_s[lr][w0];
    const int4   mv = *(const int4*)&msk_s[lr][w0];
    float iz[4];
    iz[0] = __builtin_amdgcn_rcpf(zv.x);
    iz[1] = __builtin_amdgcn_rcpf(zv.y);
    iz[2] = __builtin_amdgcn_rcpf(zv.z);
    iz[3] = __builtin_amdgcn_rcpf(zv.w);
    float mq[4];
    mq[0] = mv.x >= 0 ? 1.f : 0.f; mq[1] = mv.y >= 0 ? 1.f : 0.f;
    mq[2] = mv.z >= 0 ? 1.f : 0.f; mq[3] = mv.w >= 0 ? 1.f : 0.f;

    // row constants (z-free Jacobian algebra)
    const float dv_ = bb1 + (float)h - cy;
    const float sy  = (h == 0 || h == HH-1) ? 1.0f : 0.5f;
    const float dvf = dv_*ify;
    const float r02 = -fxv*dvf;
    const float r10 = -(fyv + dv_*dvf);
    const float dvx = dv_*ifx;
    const float fyx = fyv*ifx;
    const float duB = bb0 + (float)w0 - cx;
    const float sx0 = (w0 == 0)    ? 1.0f : 0.5f;
    const float sx3 = (w0 == WW-4) ? 1.0f : 0.5f;
    const int wl = (w0 == 0)    ? 0    : w0-1;
    const int wr = (w0 == WW-4) ? WW-1 : w0+4;

    float acc[NM];
    #pragma unroll
    for (int k = 0; k < NM; ++k) acc[k] = 0.f;

    #pragma unroll
    for (int c = 0; c < CCH; ++c) {
        const float4 ct = *(const float4*)&bf_s[c][lr+1][w0];
        const float4 up = *(const float4*)&bf_s[c][lr+2][w0];
        const float4 dn = *(const float4*)&bf_s[c][lr  ][w0];
        const float lf = bf_s[c][lr+1][wl];
        const float rt = bf_s[c][lr+1][wr];
        const float4 fvc = *(const float4*)&fin_s[c][lr][w0];
        #pragma unroll
        for (int j = 0; j < 4; ++j) {
            const float gx  = (j==0) ? (ct.y - lf  )*sx0 :
                              (j==1) ? (ct.z - ct.x)*0.5f :
                              (j==2) ? (ct.w - ct.y)*0.5f :
                                       (rt   - ct.z)*sx3;
            const float gyv = ((j==0) ? (up.x - dn.x) :
                               (j==1) ? (up.y - dn.y) :
                               (j==2) ? (up.z - dn.z) :
                                        (up.w - dn.w)) * sy;
            const float fc  = (j==0) ? fvc.x : (j==1) ? fvc.y : (j==2) ? fvc.z : fvc.w;
            const float ctj = (j==0) ? ct.x  : (j==1) ? ct.y  : (j==2) ? ct.z  : ct.w;
            const float d   = fc - ctj;
            const float gxm = gx  * mq[j];
            const float gym = gyv * mq[j];
            const float du  = duB + (float)j;
            const float izj = iz[j];
            float J0[6];
            J0[0] = gxm*(-du*dvf)            + gym*r10;
            J0[1] = gxm*(fxv + du*du*ifx)    + gym*(du*dvx);
            J0[2] = gxm*r02                  + gym*(du*fyx);
            J0[3] = gxm*(fxv*izj);
            J0[4] = gym*(fyv*izj);
            J0[5] = -(gxm*du + gym*dv_)*izj;
            #pragma unroll
            for (int i = 0; i < 6; ++i)
                #pragma unroll
                for (int jj = i; jj < 6; ++jj)
                    acc[idxA(i,jj)] += J0[i]*J0[jj];
            #pragma unroll
            for (int s = 0; s < 6; ++s) acc[21 + s] += J0[s]*d;
            #pragma unroll
            for (int s = 0; s < 6; ++s) acc[27 + c*6 + s] += J0[s];
        }
    }

    // block reduction: wave shuffle tree (deterministic) then 4-wave sum
    #pragma unroll
    for (int k = 0; k < NM; ++k) {
        float v = acc[k];
        #pragma unroll
        for (int off = 32; off > 0; off >>= 1) v += __shfl_down(v, off, 64);
        if (ln == 0) red[wv*NM + k] = v;
    }
    __syncthreads();
    if (tid < NM) {
        float s = red[tid] + red[NM + tid] + red[2*NM + tid] + red[3*NM + tid];
        // layout [b][k][tile] so k_solve's per-moment reduction is contiguous
        partials[((size_t)b*NM + tid)*NTILE + blockIdx.x] = s;
    }
}

// ---------------------------------------------------------------------------
// Stage 2: one block per batch. Threads 0..44 reduce the tile partials
// (contiguous, fp64 sum). Thread 0 runs the 5 GN iterations in fp32
// (dx ~ 1e-5; JtJ SPD => pivot-free elimination).
// ---------------------------------------------------------------------------
__global__ __launch_bounds__(64) void k_solve(
    const float* __restrict__ partials,
    const float* __restrict__ x_ini,
    const float* __restrict__ W_pose,
    const float* __restrict__ lam,
    float* __restrict__ out)
{
    const int b = blockIdx.x;
    const int tid = threadIdx.x;
    __shared__ float mom[NM];

    if (tid < NM) {
        const float* p = partials + ((size_t)b*NM + tid)*NTILE;
        double s = 0.0;
        #pragma unroll
        for (int i = 0; i < NTILE; ++i) s += (double)p[i];
        mom[tid] = (float)s;
    }
    __syncthreads();
    if (tid != 0) return;

    float A[6][6];
    for (int i = 0; i < 6; ++i)
        for (int j = i; j < 6; ++j) { float v = mom[idxA(i,j)]; A[i][j] = v; A[j][i] = v; }
    float q0[6];
    for (int s = 0; s < 6; ++s) q0[s] = mom[21 + s];
    float R0[3][6];
    for (int c = 0; c < 3; ++c) for (int s = 0; s < 6; ++s) R0[c][s] = mom[27 + c*6 + s];
    float Wp[3][6];
    for (int c = 0; c < 3; ++c) for (int s = 0; s < 6; ++s) Wp[c][s] = W_pose[c*6 + s];
    float x[6];
    for (int s = 0; s < 6; ++s) x[s] = x_ini[b*6 + s];
    const float damping = log1pf(expf(lam[0])) + 1e-6f;

    for (int it = 0; it < NGN_IT; ++it) {
        float tau[3];
        #pragma unroll
        for (int c = 0; c < 3; ++c) {
            float a = 0.f;
            #pragma unroll
            for (int s = 0; s < 6; ++s) a += x[s]*Wp[c][s];
            tau[c] = tanhf(a);
        }
        const float t0 = x[3], t1 = x[4], t2 = x[5];
        const float S[3][3] = {{0.f, -t2, t1}, {t2, 0.f, -t0}, {-t1, t0, 0.f}};

        float M[6][7];
        float PS[3][3], BS[3][3];
        #pragma unroll
        for (int i = 0; i < 3; ++i)
            #pragma unroll
            for (int j = 0; j < 3; ++j) {
                float s1 = 0.f, s2 = 0.f;
                #pragma unroll
                for (int k = 0; k < 3; ++k) { s1 += A[i][3+k]*S[k][j]; s2 += A[3+i][3+k]*S[k][j]; }
                PS[i][j] = s1; BS[i][j] = s2;
            }
        #pragma unroll
        for (int i = 0; i < 3; ++i)
            #pragma unroll
            for (int j = 0; j < 3; ++j) {
                float st = 0.f;
                #pragma unroll
                for (int k = 0; k < 3; ++k) st += S[k][i]*BS[k][j];
                M[i][j] = A[i][j] + PS[i][j] + PS[j][i] + st;
            }
        #pragma unroll
        for (int i = 0; i < 3; ++i)
            #pragma unroll
            for (int j = 0; j < 3; ++j) {
                float tr = A[i][3+j];
                #pragma unroll
                for (int k = 0; k < 3; ++k) tr += S[k][i]*A[3+k][3+j];
                M[i][3+j] = tr; M[3+j][i] = tr;
            }
        #pragma unroll
        for (int i = 0; i < 3; ++i)
            #pragma unroll
            for (int j = 0; j < 3; ++j) M[3+i][3+j] = A[3+i][3+j];
        #pragma unroll
        for (int d_ = 0; d_ < 6; ++d_) M[d_][d_] += damping;

        float base[6];
        #pragma unroll
        for (int s = 0; s < 6; ++s) {
            float v = q0[s];
            #pragma unroll
            for (int c = 0; c < 3; ++c) v -= tau[c]*R0[c][s];
            base[s] = v;
        }
        #pragma unroll
        for (int s = 0; s < 3; ++s) {
            float v = base[s];
            #pragma unroll
            for (int k = 0; k < 3; ++k) v += S[k][s]*base[3+k];
            M[s][6] = v;
        }
        #pragma unroll
        for (int s = 3; s < 6; ++s) M[s][6] = base[s];

        // pivot-free Gaussian elimination (SPD: damping>0 => nonzero pivots)
        #pragma unroll
        for (int col = 0; col < 6; ++col) {
            const float inv = 1.0f / M[col][col];
            #pragma unroll
            for (int r = col+1; r < 6; ++r) {
                const float f = M[r][col]*inv;
                #pragma unroll
                for (int cc = col; cc < 7; ++cc) M[r][cc] -= f*M[col][cc];
            }
        }
        float sol[6];
        #pragma unroll
        for (int r = 5; r >= 0; --r) {
            float s = M[r][6];
            #pragma unroll
            for (int cc = r+1; cc < 6; ++cc) s -= M[r][cc]*sol[cc];
            sol[r] = s / M[r][r];
        }
        #pragma unroll
        for (int s = 0; s < 6; ++s) x[s] += sol[s];
    }
    #pragma unroll
    for (int s = 0; s < 6; ++s) out[b*6 + s] = x[s];
}

extern "C" void kernel_launch(void* const* d_in, const int* in_sizes, int n_in,
                              void* d_out, int out_size, void* d_ws, size_t ws_size,
                              hipStream_t stream)
{
    (void)in_sizes; (void)n_in; (void)out_size; (void)ws_size;
    const float* f_inp = (const float*)d_in[0];
    const float* x_ini = (const float*)d_in[1];
    const float* depth = (const float*)d_in[2];
    const int*   fidx  = (const int*)  d_in[3];
    const float* Kmat  = (const float*)d_in[4];
    const float* bbox  = (const float*)d_in[5];
    const float* Wp    = (const float*)d_in[6];
    const float* bfeat = (const float*)d_in[7];
    const float* lam   = (const float*)d_in[8];
    float* out = (float*)d_out;

    float* partials = (float*)d_ws;

    dim3 gB(NTILE, BATCH);
    k_moments<<<gB, NTHR, 0, stream>>>(f_inp, depth, fidx, Kmat, bbox, bfeat, partials);
    k_solve<<<BATCH, 64, 0, stream>>>(partials, x_ini, Wp, lam, out);
}

// Round 7
// 33.440 us; speedup vs baseline: 1.4535x; 1.4535x over previous
//
#include <hip/hip_runtime.h>
#include <math.h>

#define BATCH 32
#define CCH 3
#define HH 256
#define WW 256
#define HW (HH*WW)
#define NGN_IT 5
#define NM 45            // 21 (A sym 6x6) + 6 (q0) + 18 (R0 3x6)
#define TROWS 4          // tile rows per block
#define NTILE (HH/TROWS) // 64 tiles per batch
#define NTHR 256
#define NROWCP 38        // staged 1KB row-copies: 18 bf + 12 f_inp + 4 depth + 4 mask

__host__ __device__ constexpr int idxA(int i, int j) { return 6*i - i*(i+1)/2 + j; } // i<=j

typedef __attribute__((address_space(1))) const unsigned int gu32;
typedef __attribute__((address_space(3))) unsigned int lu32;

__device__ __forceinline__ void gload_lds16(const float* g, float* l) {
    // per-lane global src; wave-uniform LDS base; HW writes lane i -> l + i*16
    __builtin_amdgcn_global_load_lds((gu32*)g, (lu32*)l, 16, 0, 0);
}

// DPP-fused wave-64 sum (rocPRIM sequence): pure VALU, no LDS pipe traffic.
// Result lands in lane 63.
template<int CTRL, int RMASK, int BMASK>
__device__ __forceinline__ float dpp_add(float x) {
    const int y = __builtin_amdgcn_update_dpp(0, __float_as_int(x), CTRL, RMASK, BMASK, true);
    return x + __int_as_float(y);
}
__device__ __forceinline__ float wave_sum(float x) {
    x = dpp_add<0x111, 0xf, 0xf>(x);   // row_shr:1
    x = dpp_add<0x112, 0xf, 0xf>(x);   // row_shr:2
    x = dpp_add<0x114, 0xf, 0xe>(x);   // row_shr:4  bank_mask 0xe
    x = dpp_add<0x118, 0xf, 0xc>(x);   // row_shr:8  bank_mask 0xc
    x = dpp_add<0x142, 0xa, 0xf>(x);   // row_bcast:15 row_mask 0xa
    x = dpp_add<0x143, 0xc, 0xf>(x);   // row_bcast:31 row_mask 0xc
    return x;                          // lane 63 = total
}

// ---------------------------------------------------------------------------
// Stage 1: block = 4-row tile of one batch. ALL inputs staged to LDS via
// global_load_lds (zero VGPR landing cost), ONE vmcnt drain at the barrier.
// Block reduction is DPP-based (VALU-only): rounds 2-6 were DS-pipe-bound on
// the 45x6 ds_bpermute shuffle tree (~29 us/CU of LDS-pipe serialization).
// ---------------------------------------------------------------------------
__global__ __launch_bounds__(NTHR, 4) void k_moments(
    const float* __restrict__ f_inp, const float* __restrict__ depth,
    const int* __restrict__ fidx, const float* __restrict__ Kmat,
    const float* __restrict__ bbox, const float* __restrict__ base_feat,
    float* __restrict__ partials)
{
    const int b   = blockIdx.y;
    const int h0  = blockIdx.x * TROWS;
    const int tid = threadIdx.x;

    __shared__ float bf_s [CCH][TROWS+2][WW];  // 18 KB (halo rows clamped)
    __shared__ float fin_s[CCH][TROWS][WW];    // 12 KB
    __shared__ float dpt_s[TROWS][WW];         //  4 KB
    __shared__ int   msk_s[TROWS][WW];         //  4 KB
    __shared__ float red[4*NM];                //  720 B   -> ~39.6 KB total

    const int wv = tid >> 6, ln = tid & 63;

    // --- stage all streams: wave-uniform row mapping, lane ln copies 16 B ---
    for (int o = wv; o < NROWCP; o += 4) {
        const float* src; float* dst;
        if (o < 18) {                       // base_feat rows h0-1 .. h0+4, clamped
            const int c = o / 6, k = o % 6;
            int srow = h0 - 1 + k;
            srow = srow < 0 ? 0 : (srow > HH-1 ? HH-1 : srow);
            src = base_feat + ((size_t)c*HH + srow)*WW;
            dst = &bf_s[c][k][0];
        } else if (o < 30) {                // f_inp rows h0 .. h0+3
            const int t = o - 18, c = t >> 2, r = t & 3;
            src = f_inp + (size_t)b*CCH*HW + ((size_t)c*HH + h0 + r)*WW;
            dst = &fin_s[c][r][0];
        } else if (o < 34) {                // depth
            const int r = o - 30;
            src = depth + (size_t)b*HW + (size_t)(h0 + r)*WW;
            dst = &dpt_s[r][0];
        } else {                            // mask (int, same 16B copies)
            const int r = o - 34;
            src = (const float*)(fidx + (size_t)b*HW + (size_t)(h0 + r)*WW);
            dst = (float*)&msk_s[r][0];
        }
        gload_lds16(src + ln*4, dst);
    }

    // scalar batch constants (SGPR-resident)
    const float fxv = Kmat[b*9+0], fyv = Kmat[b*9+4];
    const float cx  = Kmat[b*9+2], cy  = Kmat[b*9+5];
    const float bb0 = bbox[b*2+0], bb1 = bbox[b*2+1];
    const float ifx = __builtin_amdgcn_rcpf(fxv);
    const float ify = __builtin_amdgcn_rcpf(fyv);

    __syncthreads();   // single vmcnt(0) drain: everything in LDS

    const int lp = tid * 4;          // local pixel 0..1023
    const int lr = lp >> 8;          // local row 0..3
    const int w0 = lp & (WW-1);      // col, multiple of 4
    const int h  = h0 + lr;

    // per-thread geometry from LDS
    const float4 zv = *(const float4*)&dpt_s[lr][w0];
    const int4   mv = *(const int4*)&msk_s[lr][w0];
    float iz[4];
    iz[0] = __builtin_amdgcn_rcpf(zv.x);
    iz[1] = __builtin_amdgcn_rcpf(zv.y);
    iz[2] = __builtin_amdgcn_rcpf(zv.z);
    iz[3] = __builtin_amdgcn_rcpf(zv.w);
    float mq[4];
    mq[0] = mv.x >= 0 ? 1.f : 0.f; mq[1] = mv.y >= 0 ? 1.f : 0.f;
    mq[2] = mv.z >= 0 ? 1.f : 0.f; mq[3] = mv.w >= 0 ? 1.f : 0.f;

    // row constants (z-free Jacobian algebra)
    const float dv_ = bb1 + (float)h - cy;
    const float sy  = (h == 0 || h == HH-1) ? 1.0f : 0.5f;
    const float dvf = dv_*ify;
    const float r02 = -fxv*dvf;
    const float r10 = -(fyv + dv_*dvf);
    const float dvx = dv_*ifx;
    const float fyx = fyv*ifx;
    const float duB = bb0 + (float)w0 - cx;
    const float sx0 = (w0 == 0)    ? 1.0f : 0.5f;
    const float sx3 = (w0 == WW-4) ? 1.0f : 0.5f;
    const int wl = (w0 == 0)    ? 0    : w0-1;
    const int wr = (w0 == WW-4) ? WW-1 : w0+4;

    float acc[NM];
    #pragma unroll
    for (int k = 0; k < NM; ++k) acc[k] = 0.f;

    #pragma unroll
    for (int c = 0; c < CCH; ++c) {
        const float4 ct = *(const float4*)&bf_s[c][lr+1][w0];
        const float4 up = *(const float4*)&bf_s[c][lr+2][w0];
        const float4 dn = *(const float4*)&bf_s[c][lr  ][w0];
        const float lf = bf_s[c][lr+1][wl];
        const float rt = bf_s[c][lr+1][wr];
        const float4 fvc = *(const float4*)&fin_s[c][lr][w0];
        #pragma unroll
        for (int j = 0; j < 4; ++j) {
            const float gx  = (j==0) ? (ct.y - lf  )*sx0 :
                              (j==1) ? (ct.z - ct.x)*0.5f :
                              (j==2) ? (ct.w - ct.y)*0.5f :
                                       (rt   - ct.z)*sx3;
            const float gyv = ((j==0) ? (up.x - dn.x) :
                               (j==1) ? (up.y - dn.y) :
                               (j==2) ? (up.z - dn.z) :
                                        (up.w - dn.w)) * sy;
            const float fc  = (j==0) ? fvc.x : (j==1) ? fvc.y : (j==2) ? fvc.z : fvc.w;
            const float ctj = (j==0) ? ct.x  : (j==1) ? ct.y  : (j==2) ? ct.z  : ct.w;
            const float d   = fc - ctj;
            const float gxm = gx  * mq[j];
            const float gym = gyv * mq[j];
            const float du  = duB + (float)j;
            const float izj = iz[j];
            float J0[6];
            J0[0] = gxm*(-du*dvf)            + gym*r10;
            J0[1] = gxm*(fxv + du*du*ifx)    + gym*(du*dvx);
            J0[2] = gxm*r02                  + gym*(du*fyx);
            J0[3] = gxm*(fxv*izj);
            J0[4] = gym*(fyv*izj);
            J0[5] = -(gxm*du + gym*dv_)*izj;
            #pragma unroll
            for (int i = 0; i < 6; ++i)
                #pragma unroll
                for (int jj = i; jj < 6; ++jj)
                    acc[idxA(i,jj)] += J0[i]*J0[jj];
            #pragma unroll
            for (int s = 0; s < 6; ++s) acc[21 + s] += J0[s]*d;
            #pragma unroll
            for (int s = 0; s < 6; ++s) acc[27 + c*6 + s] += J0[s];
        }
    }

    // block reduction: DPP wave sum (VALU-only) then 4-wave LDS combine
    #pragma unroll
    for (int k = 0; k < NM; ++k) {
        const float v = wave_sum(acc[k]);
        if (ln == 63) red[wv*NM + k] = v;
    }
    __syncthreads();
    if (tid < NM) {
        float s = red[tid] + red[NM + tid] + red[2*NM + tid] + red[3*NM + tid];
        // layout [b][k][tile] so k_solve's per-moment reduction is contiguous
        partials[((size_t)b*NM + tid)*NTILE + blockIdx.x] = s;
    }
}

// ---------------------------------------------------------------------------
// Stage 2: one block per batch. Threads 0..44 reduce the tile partials
// (contiguous, fp64 sum). Thread 0 runs the 5 GN iterations in fp32
// (dx ~ 1e-5; JtJ SPD => pivot-free elimination).
// ---------------------------------------------------------------------------
__global__ __launch_bounds__(64) void k_solve(
    const float* __restrict__ partials,
    const float* __restrict__ x_ini,
    const float* __restrict__ W_pose,
    const float* __restrict__ lam,
    float* __restrict__ out)
{
    const int b = blockIdx.x;
    const int tid = threadIdx.x;
    __shared__ float mom[NM];

    if (tid < NM) {
        const float* p = partials + ((size_t)b*NM + tid)*NTILE;
        double s = 0.0;
        #pragma unroll
        for (int i = 0; i < NTILE; ++i) s += (double)p[i];
        mom[tid] = (float)s;
    }
    __syncthreads();
    if (tid != 0) return;

    float A[6][6];
    for (int i = 0; i < 6; ++i)
        for (int j = i; j < 6; ++j) { float v = mom[idxA(i,j)]; A[i][j] = v; A[j][i] = v; }
    float q0[6];
    for (int s = 0; s < 6; ++s) q0[s] = mom[21 + s];
    float R0[3][6];
    for (int c = 0; c < 3; ++c) for (int s = 0; s < 6; ++s) R0[c][s] = mom[27 + c*6 + s];
    float Wp[3][6];
    for (int c = 0; c < 3; ++c) for (int s = 0; s < 6; ++s) Wp[c][s] = W_pose[c*6 + s];
    float x[6];
    for (int s = 0; s < 6; ++s) x[s] = x_ini[b*6 + s];
    const float damping = log1pf(expf(lam[0])) + 1e-6f;

    for (int it = 0; it < NGN_IT; ++it) {
        float tau[3];
        #pragma unroll
        for (int c = 0; c < 3; ++c) {
            float a = 0.f;
            #pragma unroll
            for (int s = 0; s < 6; ++s) a += x[s]*Wp[c][s];
            tau[c] = tanhf(a);
        }
        const float t0 = x[3], t1 = x[4], t2 = x[5];
        const float S[3][3] = {{0.f, -t2, t1}, {t2, 0.f, -t0}, {-t1, t0, 0.f}};

        float M[6][7];
        float PS[3][3], BS[3][3];
        #pragma unroll
        for (int i = 0; i < 3; ++i)
            #pragma unroll
            for (int j = 0; j < 3; ++j) {
                float s1 = 0.f, s2 = 0.f;
                #pragma unroll
                for (int k = 0; k < 3; ++k) { s1 += A[i][3+k]*S[k][j]; s2 += A[3+i][3+k]*S[k][j]; }
                PS[i][j] = s1; BS[i][j] = s2;
            }
        #pragma unroll
        for (int i = 0; i < 3; ++i)
            #pragma unroll
            for (int j = 0; j < 3; ++j) {
                float st = 0.f;
                #pragma unroll
                for (int k = 0; k < 3; ++k) st += S[k][i]*BS[k][j];
                M[i][j] = A[i][j] + PS[i][j] + PS[j][i] + st;
            }
        #pragma unroll
        for (int i = 0; i < 3; ++i)
            #pragma unroll
            for (int j = 0; j < 3; ++j) {
                float tr = A[i][3+j];
                #pragma unroll
                for (int k = 0; k < 3; ++k) tr += S[k][i]*A[3+k][3+j];
                M[i][3+j] = tr; M[3+j][i] = tr;
            }
        #pragma unroll
        for (int i = 0; i < 3; ++i)
            #pragma unroll
            for (int j = 0; j < 3; ++j) M[3+i][3+j] = A[3+i][3+j];
        #pragma unroll
        for (int d_ = 0; d_ < 6; ++d_) M[d_][d_] += damping;

        float base[6];
        #pragma unroll
        for (int s = 0; s < 6; ++s) {
            float v = q0[s];
            #pragma unroll
            for (int c = 0; c < 3; ++c) v -= tau[c]*R0[c][s];
            base[s] = v;
        }
        #pragma unroll
        for (int s = 0; s < 3; ++s) {
            float v = base[s];
            #pragma unroll
            for (int k = 0; k < 3; ++k) v += S[k][s]*base[3+k];
            M[s][6] = v;
        }
        #pragma unroll
        for (int s = 3; s < 6; ++s) M[s][6] = base[s];

        // pivot-free Gaussian elimination (SPD: damping>0 => nonzero pivots)
        #pragma unroll
        for (int col = 0; col < 6; ++col) {
            const float inv = 1.0f / M[col][col];
            #pragma unroll
            for (int r = col+1; r < 6; ++r) {
                const float f = M[r][col]*inv;
                #pragma unroll
                for (int cc = col; cc < 7; ++cc) M[r][cc] -= f*M[col][cc];
            }
        }
        float sol[6];
        #pragma unroll
        for (int r = 5; r >= 0; --r) {
            float s = M[r][6];
            #pragma unroll
            for (int cc = r+1; cc < 6; ++cc) s -= M[r][cc]*sol[cc];
            sol[r] = s / M[r][r];
        }
        #pragma unroll
        for (int s = 0; s < 6; ++s) x[s] += sol[s];
    }
    #pragma unroll
    for (int s = 0; s < 6; ++s) out[b*6 + s] = x[s];
}

extern "C" void kernel_launch(void* const* d_in, const int* in_sizes, int n_in,
                              void* d_out, int out_size, void* d_ws, size_t ws_size,
                              hipStream_t stream)
{
    (void)in_sizes; (void)n_in; (void)out_size; (void)ws_size;
    const float* f_inp = (const float*)d_in[0];
    const float* x_ini = (const float*)d_in[1];
    const float* depth = (const float*)d_in[2];
    const int*   fidx  = (const int*)  d_in[3];
    const float* Kmat  = (const float*)d_in[4];
    const float* bbox  = (const float*)d_in[5];
    const float* Wp    = (const float*)d_in[6];
    const float* bfeat = (const float*)d_in[7];
    const float* lam   = (const float*)d_in[8];
    float* out = (float*)d_out;

    float* partials = (float*)d_ws;

    dim3 gB(NTILE, BATCH);
    k_moments<<<gB, NTHR, 0, stream>>>(f_inp, depth, fidx, Kmat, bbox, bfeat, partials);
    k_solve<<<BATCH, 64, 0, stream>>>(partials, x_ini, Wp, lam, out);
}